// Round 9
// baseline (362.710 us; speedup 1.0000x reference)
//
#include <hip/hip_runtime.h>
#include <cstdint>
#include <cstddef>

#define TOK 4096
#define DM 768
#define HID 2048
#define NE 8

typedef __attribute__((ext_vector_type(8))) short bf16x8;
typedef __attribute__((ext_vector_type(4))) float f32x4;

// async global->LDS: dest = wave-uniform base + lane*16; SOURCE is per-lane.
#define ASYNC16(GP, LP) \
  __builtin_amdgcn_global_load_lds((__attribute__((address_space(1))) void*)(GP), \
                                   (__attribute__((address_space(3))) void*)(LP), 16, 0, 0)

__device__ __forceinline__ unsigned short f2bf(float f) {
  unsigned int u = __float_as_uint(f);
  u += 0x7FFF + ((u >> 16) & 1);   // RNE
  return (unsigned short)(u >> 16);
}
__device__ __forceinline__ unsigned int pack2(float a, float b) {
  return (unsigned)f2bf(a) | ((unsigned)f2bf(b) << 16);
}
__device__ __forceinline__ int padded_off(const int* counts, int e) {
  int o = 0;
  for (int i = 0; i < e; ++i) o += (counts[i] + 127) & ~127;
  return o;
}

// ---------------- K_pre: gate (blocks 0..1023) + r0 weight convert ----------------
__global__ __launch_bounds__(256)
void k_pre(const float* __restrict__ x, const float* __restrict__ wgw,
           const float* __restrict__ wgb,
           const float* __restrict__ Wu, const float* __restrict__ Wv,
           const float* __restrict__ Wd,
           int* __restrict__ eidx, float* __restrict__ gatep,
           float* __restrict__ cepart,
           unsigned short* __restrict__ wub, unsigned short* __restrict__ wvb,
           unsigned short* __restrict__ wdb)
{
  __shared__ float ce_loc[4][NE];
  const int b = blockIdx.x;
  if (b < 1024) {
    // ---- gating ----
    const int lane = threadIdx.x & 63;
    const int w = threadIdx.x >> 6;
    const int t = b * 4 + w;
    float acc[NE];
#pragma unroll
    for (int e = 0; e < NE; ++e) acc[e] = 0.f;
    const float* xr = x + (size_t)t * DM;
#pragma unroll
    for (int j = 0; j < DM / 64; ++j) {
      float xv = xr[j * 64 + lane];
#pragma unroll
      for (int e = 0; e < NE; ++e) acc[e] += xv * wgw[e * DM + j * 64 + lane];
    }
#pragma unroll
    for (int e = 0; e < NE; ++e) {
      float v = acc[e];
#pragma unroll
      for (int off = 32; off >= 1; off >>= 1) v += __shfl_xor(v, off);
      acc[e] = v + wgb[e];
    }
    float mx = acc[0]; int ai = 0;
#pragma unroll
    for (int e = 1; e < NE; ++e) if (acc[e] > mx) { mx = acc[e]; ai = e; }
    float p[NE]; float se = 0.f;
#pragma unroll
    for (int e = 0; e < NE; ++e) { p[e] = expf(acc[e] - mx); se += p[e]; }
    float inv = 1.f / se;
    if (lane == 0) {
#pragma unroll
      for (int e = 0; e < NE; ++e) ce_loc[w][e] = p[e] * inv;
      eidx[t] = ai;
      gatep[t] = p[ai] * inv;
    }
    __syncthreads();
    if (threadIdx.x < NE) {
      float s = ce_loc[0][threadIdx.x] + ce_loc[1][threadIdx.x]
              + ce_loc[2][threadIdx.x] + ce_loc[3][threadIdx.x];
      cepart[b * NE + threadIdx.x] = s;
    }
  } else {
    // ---- weight convert (r0 k_convert, cb = b - 1024, 0..4607) ----
    const int cb = b - 1024;
    const int seg = cb / 1536;               // 0=Wu 1=Wv 2=Wd
    const int r = cb % 1536;
    const int e = r / 192;
    const int rem = r % 192;
    const float* W;
    unsigned short* blobbase;
    int N, nt, kt2;
    if (seg < 2) {
      N = HID; nt = rem / 12; kt2 = rem % 12;            // K=768: 12 x 64k
      W = ((seg == 0) ? Wu : Wv) + (size_t)e * DM * HID;
      blobbase = ((seg == 0) ? wub : wvb) + ((size_t)((e * 16 + nt) * 24) << 12);
    } else {
      N = DM; nt = rem / 32; kt2 = rem % 32;             // K=2048: 32 x 64k
      W = Wd + (size_t)e * HID * DM;
      blobbase = wdb + ((size_t)((e * 6 + nt) * 64) << 12);
    }
    const int t = threadIdx.x;
    const int n4 = t & 31, ko8 = t >> 5;                 // 32 n-quads x 8 k-octets
    const float* src = W + (size_t)(kt2 * 64 + ko8 * 8) * N + nt * 128 + n4 * 4;
    float4 f[8];
#pragma unroll
    for (int j = 0; j < 8; ++j) f[j] = *(const float4*)(src + (size_t)j * N);
    const int kt = kt2 * 2 + (ko8 >> 2), ko = ko8 & 3;
    unsigned short* dst = blobbase + ((size_t)kt << 12) + (size_t)(ko * 128 + n4 * 4) * 8;
#pragma unroll
    for (int i = 0; i < 4; ++i) {
      uint4 u;
      u.x = pack2(((const float*)&f[0])[i], ((const float*)&f[1])[i]);
      u.y = pack2(((const float*)&f[2])[i], ((const float*)&f[3])[i]);
      u.z = pack2(((const float*)&f[4])[i], ((const float*)&f[5])[i]);
      u.w = pack2(((const float*)&f[6])[i], ((const float*)&f[7])[i]);
      *(uint4*)(dst + i * 8) = u;
    }
  }
}

// ---------------- K_count: single-block counting sort + aux ----------------
__global__ __launch_bounds__(256)
void k_count(const int* __restrict__ eidx, const float* __restrict__ gatep,
             const float* __restrict__ cepart,
             int* __restrict__ prow_arr, int* __restrict__ tlist,
             float* __restrict__ gate_b, int* __restrict__ counts_g,
             float* __restrict__ aux_out)
{
  __shared__ int hist[256][NE];
  __shared__ float fs[256][NE];
  __shared__ int po_s[NE], cnt_s[NE];
  const int tid = threadIdx.x;
  int own[NE], v[NE], el[16];
#pragma unroll
  for (int e = 0; e < NE; ++e) own[e] = 0;
#pragma unroll
  for (int j = 0; j < 16; ++j) {
    el[j] = eidx[tid * 16 + j];
#pragma unroll
    for (int e = 0; e < NE; ++e) own[e] += (el[j] == e) ? 1 : 0;
  }
#pragma unroll
  for (int e = 0; e < NE; ++e) { v[e] = own[e]; hist[tid][e] = v[e]; }
  __syncthreads();
  for (int st = 1; st < 256; st <<= 1) {
    int add[NE];
#pragma unroll
    for (int e = 0; e < NE; ++e) add[e] = (tid >= st) ? hist[tid - st][e] : 0;
    __syncthreads();
#pragma unroll
    for (int e = 0; e < NE; ++e) { v[e] += add[e]; hist[tid][e] = v[e]; }
    __syncthreads();
  }
  if (tid == 0) {
    int o = 0;
#pragma unroll
    for (int e = 0; e < NE; ++e) {
      int c = hist[255][e];
      cnt_s[e] = c; counts_g[e] = c; po_s[e] = o;
      o += (c + 127) & ~127;
    }
  }
  __syncthreads();
  int run[NE];
#pragma unroll
  for (int e = 0; e < NE; ++e) run[e] = po_s[e] + v[e] - own[e];
#pragma unroll
  for (int j = 0; j < 16; ++j) {
    const int t = tid * 16 + j;
    const int e = el[j];
    int p = 0;
#pragma unroll
    for (int k = 0; k < NE; ++k) if (e == k) p = run[k]++;
    prow_arr[t] = p;
    tlist[p] = t;
    gate_b[p] = gatep[t];
  }
  // aux reduce
  float s[NE];
#pragma unroll
  for (int e = 0; e < NE; ++e) s[e] = 0.f;
  for (int bb = tid; bb < 1024; bb += 256)
#pragma unroll
    for (int e = 0; e < NE; ++e) s[e] += cepart[bb * NE + e];
#pragma unroll
  for (int e = 0; e < NE; ++e) fs[tid][e] = s[e];
  __syncthreads();
  for (int st = 128; st > 0; st >>= 1) {
    if (tid < st)
#pragma unroll
      for (int e = 0; e < NE; ++e) fs[tid][e] += fs[tid + st][e];
    __syncthreads();
  }
  if (tid == 0) {
    float aux = 0.f;
    for (int e = 0; e < NE; ++e)
      aux += ((float)cnt_s[e] / 4096.f) * (fs[0][e] / 4096.f);
    aux_out[0] = 0.05f * 8.f * aux;
  }
}

// ---------------- K2: scatter x rows (row-major bf16) ----------------
__global__ __launch_bounds__(256)
void k2_scatter(const float* __restrict__ x, const int* __restrict__ prow_arr,
                unsigned short* __restrict__ xb)
{
  const int b = blockIdx.x;
  const int lane = threadIdx.x & 63;
  const int w = threadIdx.x >> 6;
  const int t = b * 4 + w;
  const int prow = prow_arr[t];
  const float4* src4 = (const float4*)(x + (size_t)t * DM);
  uint2* dst = (uint2*)(xb + (size_t)prow * DM);
#pragma unroll
  for (int c = 0; c < 3; ++c) {
    float4 v = src4[lane + c * 64];
    uint2 d; d.x = pack2(v.x, v.y); d.y = pack2(v.z, v.w);
    dst[lane + c * 64] = d;
  }
}

// ---------------- FFN1: h = silu(x@Wu)*(x@Wv)*gate ----------------
// 128M x 128N, BK=64, waves 2x2, 48 KB LDS — inner loop identical to r0.
// Grid remap (panel-pin): group g=(e,tn) shares a 786-KB Bu+Bv panel; its
// tm-members get bids == g&7 (mod 8) -> same XCD, dispatched 8 apart ->
// k-lockstep march => repeat reads hit local L2 (~200cy) not LLC (~700cy).
__global__ __launch_bounds__(256, 2)
void k_ffn1(const unsigned short* __restrict__ wub, const unsigned short* __restrict__ wvb,
            const unsigned short* __restrict__ xb, const float* __restrict__ gate_b,
            const int* __restrict__ counts, unsigned short* __restrict__ h)
{
  const int bid = blockIdx.x;            // 4096 = 8 xcd-slots * 16 gh * 32 tm
  const int xs = bid & 7;
  const int q = bid >> 3;
  const int gh = q >> 5;                 // 0..15
  const int tm = q & 31;                 // 0..31
  const int g = gh * 8 + xs;             // group 0..127 (g&7 == xs)
  const int e = g >> 4;
  const int tn = g & 15;
  const int Me = counts[e];
  if (tm * 128 >= Me) return;
  const int prowbase = padded_off(counts, e) + tm * 128;

  // regions (8 KB each): [A0][Bu0][Bv0][A1][Bu1][Bv1]
  __shared__ __align__(16) unsigned short Sh[24576];

  const int tid = threadIdx.x;
  const int lane = tid & 63;
  const int wv_ = tid >> 6;
  const int wm = wv_ >> 1, wn = wv_ & 1;
  const int wu_id = __builtin_amdgcn_readfirstlane(wv_);

  f32x4 accU[4][4], accV[4][4];
#pragma unroll
  for (int i = 0; i < 4; ++i)
#pragma unroll
    for (int j = 0; j < 4; ++j)
#pragma unroll
      for (int k = 0; k < 4; ++k) { accU[i][j][k] = 0.f; accV[i][j][k] = 0.f; }

  const char* BuBase = (const char*)wub + ((size_t)((e * 16 + tn) * 24) << 13);
  const char* BvBase = (const char*)wvb + ((size_t)((e * 16 + tn) * 24) << 13);

  const char* sp[12]; size_t stp[12];
#pragma unroll
  for (int c2 = 0; c2 < 12; ++c2) {
    const int c = wu_id * 12 + c2;
    const int reg = c >> 3, i8 = c & 7;
    const int sub = (reg >= 3);
    const int rr = (reg >= 3) ? reg - 3 : reg;
    const int s = i8 * 64 + lane;
    if (rr == 0) {
      int m = s >> 2, ko = (s & 3) ^ (m & 3);
      sp[c2] = (const char*)xb + (size_t)(prowbase + m) * (DM * 2) + sub * 64 + ko * 16;
      stp[c2] = 128;
    } else {
      int n = s >> 2, ko = (s & 3) ^ (n & 3);
      const char* base = (rr == 1) ? BuBase : BvBase;
      sp[c2] = base + (size_t)sub * 8192 + (size_t)(ko * 128 + n) * 16;
      stp[c2] = 16384;
    }
  }
  const int lc = lane & 15, q2 = lane >> 4;

  for (int kt2 = 0; kt2 < 12; ++kt2) {
#pragma unroll
    for (int c2 = 0; c2 < 12; ++c2) {
      ASYNC16(sp[c2], (char*)Sh + (unsigned)((wu_id * 12 + c2) * 1024));
      sp[c2] += stp[c2];
    }
    __syncthreads();
#pragma unroll
    for (int sub = 0; sub < 2; ++sub) {
      const int sb = sub * 12288;
      bf16x8 a[4], bu[4], bv[4];
#pragma unroll
      for (int i = 0; i < 4; ++i) {
        int m = wm * 64 + i * 16 + lc;
        a[i] = *(const bf16x8*)&Sh[sb + (m * 4 + (q2 ^ (m & 3))) * 8];
      }
#pragma unroll
      for (int j = 0; j < 4; ++j) {
        int n = wn * 64 + j * 16 + lc;
        int slb = (n * 4 + (q2 ^ (n & 3))) * 8;
        bu[j] = *(const bf16x8*)&Sh[sb + 4096 + slb];
        bv[j] = *(const bf16x8*)&Sh[sb + 8192 + slb];
      }
#pragma unroll
      for (int i = 0; i < 4; ++i)
#pragma unroll
        for (int j = 0; j < 4; ++j) {
          accU[i][j] = __builtin_amdgcn_mfma_f32_16x16x32_bf16(a[i], bu[j], accU[i][j], 0, 0, 0);
          accV[i][j] = __builtin_amdgcn_mfma_f32_16x16x32_bf16(a[i], bv[j], accV[i][j], 0, 0, 0);
        }
    }
    __syncthreads();
  }
  const int colbase = tn * 128 + wn * 64;
  const int rlane = (lane >> 4) * 4;
  const int clane = lane & 15;
#pragma unroll
  for (int i = 0; i < 4; ++i) {
#pragma unroll
    for (int r = 0; r < 4; ++r) {
      int rowIn = wm * 64 + i * 16 + rlane + r;
      if (tm * 128 + rowIn < Me) {
        int prow = prowbase + rowIn;
        float g_ = gate_b[prow];
        unsigned short* hp = h + (size_t)prow * HID + colbase + clane;
#pragma unroll
        for (int j = 0; j < 4; ++j) {
          float u_ = accU[i][j][r];
          float v_ = accV[i][j][r];
          float sv = u_ / (1.f + expf(-u_));
          hp[j * 16] = f2bf(sv * v_ * g_);
        }
      }
    }
  }
}

// ---------------- FFN2: y = h @ Wd (split-K=1, plain stores), BK=64 ----------------
// Same panel-pin remap: group g2=(e,tn) shares a 512-KB wdb panel.
__global__ __launch_bounds__(256, 2)
void k_ffn2(const unsigned short* __restrict__ wdb, const unsigned short* __restrict__ h,
            const int* __restrict__ counts, const int* __restrict__ tlist,
            float* __restrict__ y)
{
  const int bid = blockIdx.x;            // 1536 = 8 xcd-slots * 6 gh * 32 tm
  const int xs = bid & 7;
  const int q = bid >> 3;
  const int gh = q >> 5;                 // 0..5
  const int tm = q & 31;                 // 0..31
  const int g = gh * 8 + xs;             // group 0..47 (g&7 == xs)
  const int e = g / 6;
  const int tn = g % 6;
  const int Me = counts[e];
  if (tm * 128 >= Me) return;
  const int prowbase = padded_off(counts, e) + tm * 128;

  // regions (8 KB each): [A0][B0][A1][B1]
  __shared__ __align__(16) unsigned short Sh[16384];

  const int tid = threadIdx.x;
  const int lane = tid & 63;
  const int wv_ = tid >> 6;
  const int wm = wv_ >> 1, wn = wv_ & 1;
  const int wu_id = __builtin_amdgcn_readfirstlane(wv_);

  f32x4 acc[4][4];
#pragma unroll
  for (int i = 0; i < 4; ++i)
#pragma unroll
    for (int j = 0; j < 4; ++j)
#pragma unroll
      for (int k = 0; k < 4; ++k) acc[i][j][k] = 0.f;

  const char* BdBase = (const char*)wdb + ((size_t)((e * 6 + tn) * 64) << 13);

  const char* sp[8]; size_t stp[8];
#pragma unroll
  for (int c2 = 0; c2 < 8; ++c2) {
    const int c = wu_id * 8 + c2;
    const int reg = c >> 3, i8 = c & 7;         // reg: 0=A0 1=B0 2=A1 3=B1
    const int sub = reg >> 1;
    const int s = i8 * 64 + lane;
    if ((reg & 1) == 0) {
      int m = s >> 2, ko = (s & 3) ^ (m & 3);
      sp[c2] = (const char*)h + (size_t)(prowbase + m) * (HID * 2)
             + sub * 64 + ko * 16;
      stp[c2] = 128;
    } else {
      int n = s >> 2, ko = (s & 3) ^ (n & 3);
      sp[c2] = BdBase + (size_t)sub * 8192 + (size_t)(ko * 128 + n) * 16;
      stp[c2] = 16384;
    }
  }
  const int lc = lane & 15, q2 = lane >> 4;

  for (int kti = 0; kti < 32; ++kti) {
#pragma unroll
    for (int c2 = 0; c2 < 8; ++c2) {
      ASYNC16(sp[c2], (char*)Sh + (unsigned)((wu_id * 8 + c2) * 1024));
      sp[c2] += stp[c2];
    }
    __syncthreads();
#pragma unroll
    for (int sub = 0; sub < 2; ++sub) {
      const int sb = sub * 8192;
      bf16x8 a[4], bfr[4];
#pragma unroll
      for (int i = 0; i < 4; ++i) {
        int m = wm * 64 + i * 16 + lc;
        a[i] = *(const bf16x8*)&Sh[sb + (m * 4 + (q2 ^ (m & 3))) * 8];
      }
#pragma unroll
      for (int j = 0; j < 4; ++j) {
        int n = wn * 64 + j * 16 + lc;
        bfr[j] = *(const bf16x8*)&Sh[sb + 4096 + (n * 4 + (q2 ^ (n & 3))) * 8];
      }
#pragma unroll
      for (int i = 0; i < 4; ++i)
#pragma unroll
        for (int j = 0; j < 4; ++j)
          acc[i][j] = __builtin_amdgcn_mfma_f32_16x16x32_bf16(a[i], bfr[j], acc[i][j], 0, 0, 0);
    }
    __syncthreads();
  }
  const int colbase = tn * 128 + wn * 64;
  const int rlane = (lane >> 4) * 4;
  const int clane = lane & 15;
#pragma unroll
  for (int i = 0; i < 4; ++i) {
#pragma unroll
    for (int r = 0; r < 4; ++r) {
      int rowIn = wm * 64 + i * 16 + rlane + r;
      if (tm * 128 + rowIn < Me) {
        int tok = tlist[prowbase + rowIn];
        float* yp = y + (size_t)tok * DM + colbase + clane;
#pragma unroll
        for (int j = 0; j < 4; ++j) yp[j * 16] = acc[i][j][r];
      }
    }
  }
}

extern "C" void kernel_launch(void* const* d_in, const int* in_sizes, int n_in,
                              void* d_out, int out_size, void* d_ws, size_t ws_size,
                              hipStream_t stream)
{
  const float* x   = (const float*)d_in[0];
  const float* wgw = (const float*)d_in[1];
  const float* wgb = (const float*)d_in[2];
  const float* Wu  = (const float*)d_in[3];
  const float* Wv  = (const float*)d_in[4];
  const float* Wd  = (const float*)d_in[5];
  float* out = (float*)d_out;

  char* ws = (char*)d_ws;
  int*   counts = (int*)(ws + 0);                         // 8 ints
  int*   eidx   = (int*)(ws + 256);                       // 4096
  float* gatep  = (float*)(ws + 16640);                   // 4096
  int*   prow   = (int*)(ws + 33024);                     // 4096
  float* cepart = (float*)(ws + 49408);                   // 1024*8
  int*   tlist  = (int*)(ws + 82176);                     // 5120 (padded rows)
  float* gate_b = (float*)(ws + 102656);                  // 5120
  unsigned short* xb  = (unsigned short*)(ws + 123136);   // 5120*768 bf16
  unsigned short* h   = (unsigned short*)(ws + 7987456);  // 5120*2048 bf16
  unsigned short* wub = (unsigned short*)(ws + 28958976); // 25.2 MB
  unsigned short* wvb = (unsigned short*)(ws + 54124800); // 25.2 MB
  unsigned short* wdb = (unsigned short*)(ws + 79290624); // 25.2 MB

  k_pre<<<1024 + 4608, 256, 0, stream>>>(x, wgw, wgb, Wu, Wv, Wd,
                                         eidx, gatep, cepart, wub, wvb, wdb);
  k_count<<<1, 256, 0, stream>>>(eidx, gatep, cepart, prow, tlist, gate_b,
                                 counts, out + (size_t)TOK * DM);
  k2_scatter<<<1024, 256, 0, stream>>>(x, prow, xb);
  k_ffn1<<<4096, 256, 0, stream>>>(wub, wvb, xb, gate_b, counts, h);
  k_ffn2<<<1536, 256, 0, stream>>>(wdb, h, counts, tlist, out);
}